// Round 10
// baseline (57.753 us; speedup 1.0000x reference)
//
#include <hip/hip_runtime.h>
#include <hip/hip_cooperative_groups.h>

namespace cg = cooperative_groups;

#define N    256
#define NH   64
#define NC   14
#define MARGIN 1e-2f      // no-clip screen slack >> f32 encoding error (~2e-6)

// ---------------------------------------------------------------------------
// Single cooperative dispatch. Per-anchor phase identical to R9's validated
// osml_main (closed-form histogram numerator + exact conservative clip screen
// + inline direct-scan fallback). Then grid.sync(); block 0 performs R9's
// osml_final reduction and writes the scalar. Writers fence before the sync
// (cross-XCD L2 visibility). All reductions fixed-order -> deterministic.
// ---------------------------------------------------------------------------
__global__ __launch_bounds__(256) void osml_all(
    const float* __restrict__ H,      // hash_features [N][NH]
    const float* __restrict__ L,      // labels        [N][NC]
    double*    __restrict__ loss_i,   // [N] workspace
    long long* __restrict__ cnt_i,    // [N] workspace
    float*     __restrict__ out)      // scalar
{
    const int i = blockIdx.x, j = threadIdx.x;

    __shared__ float     Hi[NH];
    __shared__ float     Li[NC];
    __shared__ double    ds[N];       // dist_sim row i (fp64)
    __shared__ int       dg[N];       // dist_gt row i (exact int)
    __shared__ int       hist[18];    // bins 0..14 used; 15..17 stay zero
    __shared__ unsigned  bmin[16], bmax[16];
    __shared__ double    w_num[4];
    __shared__ long long sU, sZ, sC;
    __shared__ int       sflag;

    if (j < NH)                     Hi[j]        = H[i*NH + j];
    else if (j < NH + NC)           Li[j - NH]   = L[i*NC + (j - NH)];
    else if (j >= 96  && j < 114)   hist[j - 96] = 0;
    else if (j >= 128 && j < 144)   bmin[j-128]  = 0x7f800000u;  // +inf bits
    else if (j >= 144 && j < 160)   bmax[j-144]  = 0u;
    __syncthreads();

    // fp64 dot: ds_ij = 0.5*(NH - <H_i, H_j>)  (computed once per (i,j))
    const float4* Hj4 = (const float4*)(H + j*NH);
    double a0=0.0, a1=0.0, a2=0.0, a3=0.0;
    #pragma unroll
    for (int q = 0; q < NH/4; ++q) {
        float4 v = Hj4[q];
        a0 += (double)Hi[4*q+0] * (double)v.x;
        a1 += (double)Hi[4*q+1] * (double)v.y;
        a2 += (double)Hi[4*q+2] * (double)v.z;
        a3 += (double)Hi[4*q+3] * (double)v.w;
    }
    const double dsj = 0.5 * ((double)NH - ((a0+a1)+(a2+a3)));
    ds[j] = dsj;

    // dg_ij: 0/1 dot, <=14 terms -> exact in fp32; diagonal zeroed
    float dsum = 0.f;
    #pragma unroll
    for (int c = 0; c < NC; ++c) dsum += Li[c] * L[j*NC + c];
    int dj = (int)(dsum + 0.5f);
    if (j == i) dj = 0;
    dg[j] = dj;

    atomicAdd(&hist[dj], 1);                         // exact, order-free
    const unsigned fb = __float_as_uint((float)dsj); // ds>=0 -> monotone bits
    atomicMin(&bmin[dj], fb);
    atomicMax(&bmax[dj], fb);
    __syncthreads();

    if (j == 0) {
        int c = 0, s = 0, fl = 0;
        long long U = 0, Z = 0, C = 0;
        #pragma unroll
        for (int d = 0; d < 16; ++d) {
            long long u = 0, cp = 0;
            if (d >= 1) { u += (long long)(1 << (d-1)) * hist[d-1]; cp += hist[d-1]; }
            if (d >= 2) { u += 3LL * (1 << (d-2)) * hist[d-2];      cp += hist[d-2]; }
            U += (long long)hist[d] * u;
            C += (long long)hist[d] * cp;
            Z += (long long)hist[d] * ((long long)(1 << d) * c - s);
            if (hist[d] > 0) {                       // bin d as k-side
                const float mx = __uint_as_float(bmax[d]);
                float mn = 1e30f;                    // j-side: bins d+1, d+2
                if (d+1 < 16 && hist[d+1] > 0) mn = fminf(mn, __uint_as_float(bmin[d+1]));
                if (d+2 < 16 && hist[d+2] > 0) mn = fminf(mn, __uint_as_float(bmin[d+2]));
                if (mn < mx - 5.0f + MARGIN) fl = 1;
            }
            c += hist[d]; s += hist[d] << d;
        }
        sU = U; sZ = Z; sC = C; sflag = fl;
    }
    __syncthreads();

    double num;
    if (!sflag) {
        // closed form: num_i = sum_j ds_ij*(u_j - v_j) + 5*U  (exact weights)
        long long u_j = 0;
        if (dj >= 1) u_j += (long long)(1 << (dj-1)) * hist[dj-1];
        if (dj >= 2) u_j += 3LL * (1 << (dj-2)) * hist[dj-2];
        const long long v_j = (long long)(1 << dj) * (hist[dj+1] + 3*hist[dj+2]);
        num = dsj * (double)(u_j - v_j);
    } else {
        // inline exact fallback (R3-validated scan body); block-uniform branch
        const int    g2j  = 1 << dj;
        const double dsj5 = dsj + 5.0;
        const double r1   = (double)(g2j >> 1);        // dk == dj-1
        const double r2   = (double)(3 * (g2j >> 2));  // dk == dj-2
        double n0 = 0.0, n1 = 0.0;
#define OSML_BODY(O, ACC) {                                        \
            const int    dd = dj - dg[kk + (O)];                   \
            double       w  = (dd == 1) ? r1 : ((dd == 2) ? r2 : 0.0); \
            const double tt = dsj5 - ds[kk + (O)];                 \
            w = (tt > 0.0) ? w : 0.0;                              \
            ACC = fma(w, tt, ACC); }
        #pragma unroll 8
        for (int kk = 0; kk < N; kk += 2) {
            OSML_BODY(0, n0)
            OSML_BODY(1, n1)
        }
#undef OSML_BODY
        num = n0 + n1;
    }

    // fixed-order wave reduce, then 4 wave-partials summed sequentially
    #pragma unroll
    for (int off = 32; off > 0; off >>= 1)
        num += __shfl_down(num, off, 64);
    if ((j & 63) == 0) w_num[j >> 6] = num;
    __syncthreads();
    if (j == 0) {
        double total = ((w_num[0]+w_num[1])+(w_num[2]+w_num[3]));
        if (!sflag) total += 5.0 * (double)sU;       // constant term, closed path
        loss_i[i] = (sZ > 0) ? total / (double)sZ : 0.0;
        cnt_i[i]  = sC;
        __threadfence();   // release: flush dirty L2 lines to coherence point
    }

    cg::this_grid().sync();   // 256 blocks, 1/CU -> co-resident; includes fences

    // ---- block 0: final deterministic reduction over the 256 anchors ----
    if (i == 0) {
        const int t = j;
        double    l = loss_i[t];
        long long c = cnt_i[t];
        #pragma unroll
        for (int off = 32; off > 0; off >>= 1) {
            l += __shfl_down(l, off, 64);
            c += __shfl_down(c, off, 64);
        }
        __shared__ double    sl[4];
        __shared__ long long sc[4];
        if ((t & 63) == 0) { sl[t >> 6] = l; sc[t >> 6] = c; }
        __syncthreads();
        if (t == 0) {
            const double    losses = (sl[0]+sl[1]) + (sl[2]+sl[3]);
            const long long counts = sc[0]+sc[1]+sc[2]+sc[3];
            out[0] = (float)((counts > 0) ? losses / (double)counts : losses);
        }
    }
}

extern "C" void kernel_launch(void* const* d_in, const int* in_sizes, int n_in,
                              void* d_out, int out_size, void* d_ws, size_t ws_size,
                              hipStream_t stream) {
    const float* H   = (const float*)d_in[0];  // hash_features [256][64] fp32
    const float* L   = (const float*)d_in[1];  // labels        [256][14] fp32
    float*       out = (float*)d_out;          // scalar fp32

    double*    loss = (double*)d_ws;              // 256 * 8 B
    long long* cnt  = (long long*)(loss + N);     // 256 * 8 B

    void* args[] = { (void*)&H, (void*)&L, (void*)&loss, (void*)&cnt, (void*)&out };
    hipLaunchCooperativeKernel((const void*)osml_all, dim3(N), dim3(256),
                               args, 0, stream);
}

// Round 11
// 20.926 us; speedup vs baseline: 2.7598x; 2.7598x over previous
//
#include <hip/hip_runtime.h>

#define N    256
#define NH   64
#define NC   14
#define MARGIN 1e-2f      // no-clip screen slack >> f32 encoding error (~2e-6)

// ---------------------------------------------------------------------------
// Kernel 1: one block per anchor i, 256 threads (thread j owns column j).
// R9-validated math; latency-trimmed structure:
//  - H_i / L_i rows read directly from global (block-uniform -> scalar loads),
//    no LDS staging barrier.
//  - 16-bin histogram scan computed REDUNDANTLY by every thread (identical
//    inputs -> identical results) instead of serial thread-0 + barrier.
//  - 3 barriers total: (A) zero-init + ds/dg visible, (B) atomics done,
//    (C) wave partials visible.
// Closed-form numerator from the label-distance histogram (exact integer
// weights) + exact conservative clip screen; flagged blocks fall back inline
// to the direct 256-iter scan. Z and keep-count always closed-form (exact).
// All reductions fixed-order -> deterministic.
// ---------------------------------------------------------------------------
__global__ __launch_bounds__(256) void osml_main(
    const float* __restrict__ H,      // hash_features [N][NH]
    const float* __restrict__ L,      // labels        [N][NC]
    double*    __restrict__ loss_i,   // [N]
    long long* __restrict__ cnt_i)    // [N]
{
    const int i = blockIdx.x, j = threadIdx.x;

    __shared__ double    ds[N];       // dist_sim row i (fp64)
    __shared__ int       dg[N];       // dist_gt row i (exact int)
    __shared__ int       hist[18];    // bins 0..14 used; 15..17 stay zero
    __shared__ unsigned  bmin[16], bmax[16];
    __shared__ double    w_num[4];

    // fp64 dot: ds_ij = 0.5*(NH - <H_i, H_j>). H_i row is block-uniform.
    const float4* Hj4 = (const float4*)(H + j*NH);
    const float4* Hi4 = (const float4*)(H + i*NH);
    double a0=0.0, a1=0.0, a2=0.0, a3=0.0;
    #pragma unroll
    for (int q = 0; q < NH/4; ++q) {
        const float4 hj = Hj4[q];
        const float4 hi = Hi4[q];
        a0 += (double)hi.x * (double)hj.x;
        a1 += (double)hi.y * (double)hj.y;
        a2 += (double)hi.z * (double)hj.z;
        a3 += (double)hi.w * (double)hj.w;
    }
    const double dsj = 0.5 * ((double)NH - ((a0+a1)+(a2+a3)));

    // dg_ij: 0/1 dot, <=14 terms -> exact in fp32; diagonal zeroed
    float dsum = 0.f;
    #pragma unroll
    for (int c = 0; c < NC; ++c) dsum += L[i*NC + c] * L[j*NC + c];
    int dj = (int)(dsum + 0.5f);
    if (j == i) dj = 0;

    ds[j] = dsj;
    dg[j] = dj;
    if (j < 18)                 hist[j]      = 0;
    else if (j >= 32 && j < 48) bmin[j - 32] = 0x7f800000u;  // +inf bits
    else if (j >= 48 && j < 64) bmax[j - 48] = 0u;
    __syncthreads();                                 // (A)

    atomicAdd(&hist[dj], 1);                         // exact, order-free
    const unsigned fb = __float_as_uint((float)dsj); // ds>=0 -> monotone bits
    atomicMin(&bmin[dj], fb);
    atomicMax(&bmax[dj], fb);
    __syncthreads();                                 // (B)

    // redundant per-thread 16-bin scan: identical LDS inputs + identical ops
    // -> every thread derives the same U, Z, C, fl (block-uniform).
    int c = 0, s = 0, fl = 0;
    long long U = 0, Z = 0, C = 0;
    #pragma unroll
    for (int d = 0; d < 16; ++d) {
        const int hd = hist[d];
        long long u = 0, cp = 0;
        if (d >= 1) { u += (long long)(1 << (d-1)) * hist[d-1]; cp += hist[d-1]; }
        if (d >= 2) { u += 3LL * (1 << (d-2)) * hist[d-2];      cp += hist[d-2]; }
        U += (long long)hd * u;
        C += (long long)hd * cp;
        Z += (long long)hd * ((long long)(1 << d) * c - s);
        if (hd > 0) {                        // bin d as k-side
            const float mx = __uint_as_float(bmax[d]);
            float mn = 1e30f;                // j-side: bins d+1, d+2
            if (d+1 < 16 && hist[d+1] > 0) mn = fminf(mn, __uint_as_float(bmin[d+1]));
            if (d+2 < 16 && hist[d+2] > 0) mn = fminf(mn, __uint_as_float(bmin[d+2]));
            if (mn < mx - 5.0f + MARGIN) fl = 1;
        }
        c += hd; s += hd << d;
    }

    double num;
    if (!fl) {
        // closed form: num_i = sum_j ds_ij*(u_j - v_j) + 5*U  (exact weights)
        long long u_j = 0;
        if (dj >= 1) u_j += (long long)(1 << (dj-1)) * hist[dj-1];
        if (dj >= 2) u_j += 3LL * (1 << (dj-2)) * hist[dj-2];
        const long long v_j = (long long)(1 << dj) * (hist[dj+1] + 3*hist[dj+2]);
        num = dsj * (double)(u_j - v_j);
    } else {
        // inline exact fallback (R3-validated scan body); block-uniform branch
        const int    g2j  = 1 << dj;
        const double dsj5 = dsj + 5.0;
        const double r1   = (double)(g2j >> 1);        // dk == dj-1
        const double r2   = (double)(3 * (g2j >> 2));  // dk == dj-2
        double n0 = 0.0, n1 = 0.0;
#define OSML_BODY(O, ACC) {                                        \
            const int    dd = dj - dg[kk + (O)];                   \
            double       w  = (dd == 1) ? r1 : ((dd == 2) ? r2 : 0.0); \
            const double tt = dsj5 - ds[kk + (O)];                 \
            w = (tt > 0.0) ? w : 0.0;                              \
            ACC = fma(w, tt, ACC); }
        #pragma unroll 8
        for (int kk = 0; kk < N; kk += 2) {
            OSML_BODY(0, n0)
            OSML_BODY(1, n1)
        }
#undef OSML_BODY
        num = n0 + n1;
    }

    // fixed-order wave reduce, then 4 wave-partials summed sequentially
    #pragma unroll
    for (int off = 32; off > 0; off >>= 1)
        num += __shfl_down(num, off, 64);
    if ((j & 63) == 0) w_num[j >> 6] = num;
    __syncthreads();                                 // (C)
    if (j == 0) {
        double total = ((w_num[0]+w_num[1])+(w_num[2]+w_num[3]));
        if (!fl) total += 5.0 * (double)U;           // constant term, closed path
        loss_i[i] = (Z > 0) ? total / (double)Z : 0.0;
        cnt_i[i]  = C;
    }
}

// ---------------------------------------------------------------------------
// Kernel 2: ONE wave, no LDS, no barriers. Lane t folds anchors
// {t, t+64, t+128, t+192} in fixed order, then a 6-step shuffle reduce.
// ---------------------------------------------------------------------------
__global__ __launch_bounds__(64) void osml_final(
    const double*    __restrict__ loss_i,
    const long long* __restrict__ cnt_i,
    float*           __restrict__ out)
{
    const int t = threadIdx.x;
    double    l = (loss_i[t] + loss_i[t+64]) + (loss_i[t+128] + loss_i[t+192]);
    long long c = (cnt_i[t]  + cnt_i[t+64])  + (cnt_i[t+128]  + cnt_i[t+192]);
    #pragma unroll
    for (int off = 32; off > 0; off >>= 1) {
        l += __shfl_down(l, off, 64);
        c += __shfl_down(c, off, 64);
    }
    if (t == 0)
        out[0] = (float)((c > 0) ? l / (double)c : l);
}

extern "C" void kernel_launch(void* const* d_in, const int* in_sizes, int n_in,
                              void* d_out, int out_size, void* d_ws, size_t ws_size,
                              hipStream_t stream) {
    const float* H   = (const float*)d_in[0];  // hash_features [256][64] fp32
    const float* L   = (const float*)d_in[1];  // labels        [256][14] fp32
    float*       out = (float*)d_out;          // scalar fp32

    double*    loss = (double*)d_ws;             // 256 * 8 B
    long long* cnt  = (long long*)(loss + N);    // 256 * 8 B

    osml_main<<<N, 256, 0, stream>>>(H, L, loss, cnt);
    osml_final<<<1, 64, 0, stream>>>(loss, cnt, out);
}